// Round 12
// baseline (192.201 us; speedup 1.0000x reference)
//
#include <hip/hip_runtime.h>

// VQ codebook via MFMA: z_e (262144,64) f32, embeddings (512,64) f32.
// Outputs (flat f32): z_q_st [N*D], indices-as-float [N], loss [1].
//
// R12 = R11 with TWO E-tiles per K-loop iteration (16 iters instead of 32).
// R11 post-mortem: per-iter work (~150cyc) < L2 prefetch latency (~300cyc) ->
// every wave stalled at the vmcnt+barrier each of 32 iterations (60us stall,
// MfmaUtil 18.5%). 2 tiles/iter doubles compute per round-trip (12 MFMA +
// ~50 VALU) and halves barrier count; tile-B fragments reuse tile-A's
// registers (live set stays ~54 < the 64-VGPR allocator cap from R1-R7).
// Everything else (bf16 two-term split, gap guard + exact rescan, epilogue
// kernels) identical to R11 (passed, absmax 0).

typedef short  bf16x8 __attribute__((ext_vector_type(8)));
typedef float  f32x4  __attribute__((ext_vector_type(4)));

static constexpr int N_TOK = 262144;
static constexpr int K     = 512;
static constexpr int D     = 64;
static constexpr float THRESH = 0.02f;
static constexpr int NBLK_OUT = N_TOK / 64;   // 4096 (kernel C blocks)

// ws layout (bytes)
static constexpr size_t WS_ESQ   = 0;         //  512 f32
static constexpr size_t WS_BL    = 2048;      // 4096 f32
static constexpr size_t WS_CNT   = 18432;     // 1 uint
static constexpr size_t WS_EFRAG = 18448;     // 65536 u16
static constexpr size_t WS_BIDX  = 149520;    // 262144 int
static constexpr size_t WS_LIST  = 1198096;   // 262144 uint

// ---- prep 0: esq[k] = ||e_k||^2 (f32) --------------------------------------
__global__ void esq_kernel(const float* __restrict__ emb, float* __restrict__ esq) {
  int k = threadIdx.x;
  if (k < K) {
    const float4* row = reinterpret_cast<const float4*>(emb + (size_t)k * D);
    float s = 0.f;
#pragma unroll
    for (int i = 0; i < D / 4; ++i) {
      float4 v = row[i];
      s = fmaf(v.x, v.x, s); s = fmaf(v.y, v.y, s);
      s = fmaf(v.z, v.z, s); s = fmaf(v.w, v.w, s);
    }
    esq[k] = s;
  }
}

// ---- prep 1: E' = -2E -> bf16 hi/lo in A-fragment order --------------------
__global__ __launch_bounds__(512) void efrag_kernel(
    const float* __restrict__ emb, unsigned short* __restrict__ ef) {
  int idx  = blockIdx.x * 512 + threadIdx.x;   // 32768 = 512 codes * 64 d
  int code = idx >> 6, d = idx & 63;
  float s  = -2.0f * emb[code * 64 + d];
  unsigned u  = __float_as_uint(s);
  unsigned hi = (u + 0x7FFFu + ((u >> 16) & 1u)) >> 16;       // RNE bf16
  float lof   = s - __uint_as_float(hi << 16);
  unsigned v2 = __float_as_uint(lof);
  unsigned lo = (v2 + 0x7FFFu + ((v2 >> 16) & 1u)) >> 16;     // RNE bf16
  int tile = code >> 4, row = code & 15;
  int c = (d >> 5) & 1, g = (d >> 3) & 3, i = d & 7;
  int lane = row + (g << 4);
  size_t base = ((size_t)tile * 256 + (size_t)c * 128) * 8;
  ef[base + (size_t)(0 * 64 + lane) * 8 + i] = (unsigned short)hi;
  ef[base + (size_t)(1 * 64 + lane) * 8 + i] = (unsigned short)lo;
}

// ---- kernel A: MFMA distances + best/second/argmin + flag ------------------
__global__ __launch_bounds__(256) void vq_mfma(
    const float* __restrict__ z_e, const unsigned short* __restrict__ efrag,
    const float* __restrict__ esq_g, int* __restrict__ bidx,
    unsigned* __restrict__ list, unsigned* __restrict__ cnt) {
  __shared__ float zs[64 * 68];                    // 17408 B
  __shared__ float esql[K];                        // 2048 B
  __shared__ __align__(16) short lds_eb[2][4096];  // 2 x 8KB (2 tiles each)

  const int t = threadIdx.x;
  const int gtok0 = blockIdx.x * 64;

  // Stage 64 z rows (coalesced float4) + esq.
  {
    const float4* Z4 = reinterpret_cast<const float4*>(z_e + (size_t)gtok0 * D);
#pragma unroll
    for (int i = 0; i < 4; ++i) {
      int i4 = t + i * 256;
      float4 v = Z4[i4];
      int tk = i4 >> 4, d4 = (i4 & 15) << 2;
      *reinterpret_cast<float4*>(&zs[tk * 68 + d4]) = v;
    }
    esql[t] = esq_g[t];
    esql[t + 256] = esq_g[t + 256];
  }
  __syncthreads();

  const int l = t & 63, w = t >> 6;
  const int g = l >> 4, g4 = g << 2;
  const int lr = (w << 4) + (l & 15);

  // B-frags: z[tok][32c + g*8 + i] -> bf16 hi/lo (RNE split, = efrag's).
  bf16x8 zh0, zl0, zh1, zl1;
  {
    float a[8], b[8];
    const float* zp0 = &zs[lr * 68 + g * 8];
    const float* zp1 = zp0 + 32;
    float4 q;
    q = *reinterpret_cast<const float4*>(zp0);     a[0]=q.x;a[1]=q.y;a[2]=q.z;a[3]=q.w;
    q = *reinterpret_cast<const float4*>(zp0 + 4); a[4]=q.x;a[5]=q.y;a[6]=q.z;a[7]=q.w;
    q = *reinterpret_cast<const float4*>(zp1);     b[0]=q.x;b[1]=q.y;b[2]=q.z;b[3]=q.w;
    q = *reinterpret_cast<const float4*>(zp1 + 4); b[4]=q.x;b[5]=q.y;b[6]=q.z;b[7]=q.w;
#pragma unroll
    for (int i = 0; i < 8; ++i) {
      unsigned u  = __float_as_uint(a[i]);
      unsigned hi = (u + 0x7FFFu + ((u >> 16) & 1u)) >> 16;
      float lof   = a[i] - __uint_as_float(hi << 16);
      unsigned v2 = __float_as_uint(lof);
      unsigned lo = (v2 + 0x7FFFu + ((v2 >> 16) & 1u)) >> 16;
      zh0[i] = (short)hi; zl0[i] = (short)lo;
      u  = __float_as_uint(b[i]);
      hi = (u + 0x7FFFu + ((u >> 16) & 1u)) >> 16;
      lof = b[i] - __uint_as_float(hi << 16);
      v2 = __float_as_uint(lof);
      lo = (v2 + 0x7FFFu + ((v2 >> 16) & 1u)) >> 16;
      zh1[i] = (short)hi; zl1[i] = (short)lo;
    }
  }

  const bf16x8* EF = reinterpret_cast<const bf16x8*>(efrag);
  // Prime tile-pair 0 into buffer 0.
  {
    bf16x8 p0 = EF[t];
    bf16x8 p1 = EF[256 + t];
    bf16x8* dst = reinterpret_cast<bf16x8*>(&lds_eb[0][0]);
    dst[t] = p0;
    dst[256 + t] = p1;
  }
  __syncthreads();

  float best = 3.402823466e38f, second = 3.402823466e38f;
  int bidxv = 0;
  int buf = 0;

#define ARGMIN4(C, BASE)                                    \
  {                                                         \
    _Pragma("unroll")                                       \
    for (int r = 0; r < 4; ++r) {                           \
      float v = (C)[r];                                     \
      bool lt = v < best;                                   \
      float mn = fminf(second, v);                          \
      second = lt ? best : mn;                              \
      bidxv  = lt ? ((BASE) + r) : bidxv;                   \
      best   = lt ? v : best;                               \
    }                                                       \
  }

  for (int it = 0; it < 16; ++it) {
    bf16x8 nxt0, nxt1;
    if (it < 15) {                                  // prefetch next tile-pair
      nxt0 = EF[(size_t)(it + 1) * 512 + t];
      nxt1 = EF[(size_t)(it + 1) * 512 + 256 + t];
    }
    const bf16x8* eb = reinterpret_cast<const bf16x8*>(&lds_eb[buf][0]);

    // ---- tile A = 2*it ----
    {
      f32x4 C = *reinterpret_cast<const f32x4*>(&esql[(2 * it) * 16 + g4]);
      bf16x8 a0 = eb[l], b0 = eb[64 + l], a1 = eb[128 + l], b1 = eb[192 + l];
      C = __builtin_amdgcn_mfma_f32_16x16x32_bf16(a0, zh0, C, 0, 0, 0);
      C = __builtin_amdgcn_mfma_f32_16x16x32_bf16(a0, zl0, C, 0, 0, 0);
      C = __builtin_amdgcn_mfma_f32_16x16x32_bf16(b0, zh0, C, 0, 0, 0);
      C = __builtin_amdgcn_mfma_f32_16x16x32_bf16(a1, zh1, C, 0, 0, 0);
      C = __builtin_amdgcn_mfma_f32_16x16x32_bf16(a1, zl1, C, 0, 0, 0);
      C = __builtin_amdgcn_mfma_f32_16x16x32_bf16(b1, zh1, C, 0, 0, 0);
      ARGMIN4(C, (2 * it) * 16 + g4)
    }
    // ---- tile B = 2*it+1 ----
    {
      f32x4 C = *reinterpret_cast<const f32x4*>(&esql[(2 * it + 1) * 16 + g4]);
      bf16x8 a0 = eb[256 + l], b0 = eb[320 + l],
             a1 = eb[384 + l], b1 = eb[448 + l];
      C = __builtin_amdgcn_mfma_f32_16x16x32_bf16(a0, zh0, C, 0, 0, 0);
      C = __builtin_amdgcn_mfma_f32_16x16x32_bf16(a0, zl0, C, 0, 0, 0);
      C = __builtin_amdgcn_mfma_f32_16x16x32_bf16(b0, zh0, C, 0, 0, 0);
      C = __builtin_amdgcn_mfma_f32_16x16x32_bf16(a1, zh1, C, 0, 0, 0);
      C = __builtin_amdgcn_mfma_f32_16x16x32_bf16(a1, zl1, C, 0, 0, 0);
      C = __builtin_amdgcn_mfma_f32_16x16x32_bf16(b1, zh1, C, 0, 0, 0);
      ARGMIN4(C, (2 * it + 1) * 16 + g4)
    }

    if (it < 15) {
      bf16x8* dst = reinterpret_cast<bf16x8*>(&lds_eb[buf ^ 1][0]);
      dst[t] = nxt0;
      dst[256 + t] = nxt1;
    }
    __syncthreads();
    buf ^= 1;
  }
#undef ARGMIN4

  // Reduce token's 4 lanes {l, l+16, l+32, l+48}; ties -> smaller code.
#pragma unroll
  for (int mask = 16; mask <= 32; mask <<= 1) {
    float ob = __shfl_xor(best, mask);
    int   oi = __shfl_xor(bidxv, mask);
    float os = __shfl_xor(second, mask);
    float hi2 = fmaxf(best, ob);
    second = fminf(second, fminf(os, hi2));
    bool take = (ob < best) || (ob == best && oi < bidxv);
    best  = take ? ob : best;
    bidxv = take ? oi : bidxv;
  }

  if (l < 16) {
    int n = gtok0 + (w << 4) + l;
    bool flag = (second - best) < THRESH;      // gap guard (>=6x err bound)
    bidx[n] = bidxv | (flag ? 0x40000000 : 0);
    if (flag) {
      unsigned pos = atomicAdd(cnt, 1u);
      list[pos] = (unsigned)n;
    }
  }
}

// ---- kernel B: exact f32 rescan of flagged tokens (wave per token) ---------
__global__ __launch_bounds__(256) void vq_fix(
    const float* __restrict__ z_e, const float* __restrict__ emb,
    const float* __restrict__ esq_g, int* __restrict__ bidx,
    const unsigned* __restrict__ list, const unsigned* __restrict__ cnt) {
  const int l = threadIdx.x & 63;
  const int wid = blockIdx.x * 4 + (threadIdx.x >> 6);
  const unsigned n_flag = *cnt;
  for (unsigned j = wid; j < n_flag; j += 256 * 4) {
    const int n = (int)list[j];
    const float4* zr = reinterpret_cast<const float4*>(z_e + (size_t)n * D);
    float acc[8];
#pragma unroll
    for (int m = 0; m < 8; ++m) acc[m] = 0.f;
#pragma unroll 4
    for (int i = 0; i < 16; ++i) {
      float4 z4 = zr[i];
#pragma unroll
      for (int m = 0; m < 8; ++m) {
        const float4 e4 = *reinterpret_cast<const float4*>(
            emb + (size_t)(l + 64 * m) * D + 4 * i);
        acc[m] = fmaf(z4.x, e4.x, acc[m]);
        acc[m] = fmaf(z4.y, e4.y, acc[m]);
        acc[m] = fmaf(z4.z, e4.z, acc[m]);
        acc[m] = fmaf(z4.w, e4.w, acc[m]);
      }
    }
    float best = 3.402823466e38f; int bid = 0;
#pragma unroll
    for (int m = 0; m < 8; ++m) {
      float s = fmaf(-2.f, acc[m], esq_g[l + 64 * m]);
      if (s < best) { best = s; bid = l + 64 * m; }
    }
#pragma unroll
    for (int mask = 1; mask <= 32; mask <<= 1) {     // lexicographic min
      float ob = __shfl_xor(best, mask);
      int   oi = __shfl_xor(bid, mask);
      bool take = (ob < best) || (ob == best && oi < bid);
      best = take ? ob : best;
      bid  = take ? oi : bid;
    }
    if (l == 0) bidx[n] = bid;
  }
}

// ---- kernel C: gather + z_q_st + idx float + deterministic loss ------------
__global__ __launch_bounds__(256) void vq_out(
    const float* __restrict__ z_e, const float* __restrict__ emb,
    const int* __restrict__ bidx, float* __restrict__ out_zq,
    float* __restrict__ out_idx, float* __restrict__ block_loss) {
  __shared__ float wsm[4];
  const int t = threadIdx.x;
  const int tokE = t >> 2, q = t & 3;
  const int n = blockIdx.x * 64 + tokE;
  const int bi = bidx[n] & 511;
  const float4* er = reinterpret_cast<const float4*>(emb + (size_t)bi * D);
  const float4* zr = reinterpret_cast<const float4*>(z_e + (size_t)n * D);
  float4* orow = reinterpret_cast<float4*>(out_zq + (size_t)n * D);
  float lsum = 0.f;
#pragma unroll
  for (int j = 0; j < 4; ++j) {
    int i = 4 * q + j;
    float4 Q = er[i], Z = zr[i];
    float dx = Q.x - Z.x, dy = Q.y - Z.y, dz = Q.z - Z.z, dw = Q.w - Z.w;
    float4 st;
    st.x = Z.x + dx; st.y = Z.y + dy; st.z = Z.z + dz; st.w = Z.w + dw;
    orow[i] = st;
    lsum = fmaf(dx, dx, lsum); lsum = fmaf(dy, dy, lsum);
    lsum = fmaf(dz, dz, lsum); lsum = fmaf(dw, dw, lsum);
  }
  if (q == 0) out_idx[n] = (float)bi;
  float s = lsum;
#pragma unroll
  for (int off = 32; off > 0; off >>= 1) s += __shfl_xor(s, off, 64);
  if ((t & 63) == 0) wsm[t >> 6] = s;
  __syncthreads();
  if (t == 0) block_loss[blockIdx.x] = ((wsm[0] + wsm[1]) + wsm[2]) + wsm[3];
}

// ---- finalize loss (deterministic tree) ------------------------------------
__global__ __launch_bounds__(256) void loss_finalize(
    const float* __restrict__ bl, float* __restrict__ out_loss) {
  __shared__ float sm[256];
  float s = 0.f;
  for (int i = threadIdx.x; i < NBLK_OUT; i += 256) s += bl[i];
  sm[threadIdx.x] = s;
  __syncthreads();
#pragma unroll
  for (int off = 128; off > 0; off >>= 1) {
    if (threadIdx.x < off) sm[threadIdx.x] += sm[threadIdx.x + off];
    __syncthreads();
  }
  if (threadIdx.x == 0) out_loss[0] = sm[0] * (1.0f / 16777216.0f);  // /(N*D)
}

extern "C" void kernel_launch(void* const* d_in, const int* in_sizes, int n_in,
                              void* d_out, int out_size, void* d_ws, size_t ws_size,
                              hipStream_t stream) {
  const float* z_e = (const float*)d_in[0];
  const float* emb = (const float*)d_in[1];

  float* out      = (float*)d_out;
  float* out_zq   = out;                          // N*D
  float* out_idx  = out + (size_t)N_TOK * D;      // N
  float* out_loss = out_idx + N_TOK;              // 1

  char* wsb = (char*)d_ws;
  float*          esqp = (float*)(wsb + WS_ESQ);
  float*          bl   = (float*)(wsb + WS_BL);
  unsigned*       cntp = (unsigned*)(wsb + WS_CNT);
  unsigned short* ef   = (unsigned short*)(wsb + WS_EFRAG);
  int*            bidx = (int*)(wsb + WS_BIDX);
  unsigned*       list = (unsigned*)(wsb + WS_LIST);

  hipMemsetAsync(cntp, 0, 4, stream);
  esq_kernel<<<1, 512, 0, stream>>>(emb, esqp);
  efrag_kernel<<<64, 512, 0, stream>>>(emb, ef);
  vq_mfma<<<N_TOK / 64, 256, 0, stream>>>(z_e, ef, esqp, bidx, list, cntp);
  vq_fix<<<256, 256, 0, stream>>>(z_e, emb, esqp, bidx, list, cntp);
  vq_out<<<NBLK_OUT, 256, 0, stream>>>(z_e, emb, bidx, out_zq, out_idx, bl);
  loss_finalize<<<1, 256, 0, stream>>>(bl, out_loss);
}

// Round 13
// 160.294 us; speedup vs baseline: 1.1991x; 1.1991x over previous
//
#include <hip/hip_runtime.h>

// VQ codebook via MFMA: z_e (262144,64) f32, embeddings (512,64) f32.
// Outputs (flat f32): z_q_st [N*D], indices-as-float [N], loss [1].
//
// R13: 2 token-groups per wave (32 tokens) -> every E-fragment read feeds two
// independent MFMA chains (24 MFMA / tile-pair); z-frags built from direct
// coalesced global reads (zs LDS tile deleted); E-tiles staged via
// global_load_lds width=16 (no prefetch VGPRs, no ds_write). LDS 18.4KB ->
// 8 blocks/CU (32 waves/CU). Steady live set ~60 VGPR < the 64 allocator cap
// (R1-R7 evidence). R12 lesson: barriers weren't the limit; occupancy x
// arithmetic-intensity is. MFMA order/split/guard bitwise = R12 (absmax 0).

typedef short  bf16x8 __attribute__((ext_vector_type(8)));
typedef float  f32x4  __attribute__((ext_vector_type(4)));

static constexpr int N_TOK = 262144;
static constexpr int K     = 512;
static constexpr int D     = 64;
static constexpr float THRESH = 0.02f;
static constexpr int NBLK_OUT = N_TOK / 64;   // 4096 (kernel C blocks)

// ws layout (bytes)
static constexpr size_t WS_ESQ   = 0;         //  512 f32
static constexpr size_t WS_BL    = 2048;      // 4096 f32
static constexpr size_t WS_CNT   = 18432;     // 1 uint
static constexpr size_t WS_EFRAG = 18448;     // 65536 u16
static constexpr size_t WS_BIDX  = 149520;    // 262144 int
static constexpr size_t WS_LIST  = 1198096;   // 262144 uint

#define GLDS16(G, L) __builtin_amdgcn_global_load_lds(                    \
    (const __attribute__((address_space(1))) void*)(G),                   \
    (__attribute__((address_space(3))) void*)(L), 16, 0, 0)

// ---- prep 0: esq[k] = ||e_k||^2 (f32) --------------------------------------
__global__ void esq_kernel(const float* __restrict__ emb, float* __restrict__ esq) {
  int k = threadIdx.x;
  if (k < K) {
    const float4* row = reinterpret_cast<const float4*>(emb + (size_t)k * D);
    float s = 0.f;
#pragma unroll
    for (int i = 0; i < D / 4; ++i) {
      float4 v = row[i];
      s = fmaf(v.x, v.x, s); s = fmaf(v.y, v.y, s);
      s = fmaf(v.z, v.z, s); s = fmaf(v.w, v.w, s);
    }
    esq[k] = s;
  }
}

// ---- prep 1: E' = -2E -> bf16 hi/lo in A-fragment order --------------------
__global__ __launch_bounds__(512) void efrag_kernel(
    const float* __restrict__ emb, unsigned short* __restrict__ ef) {
  int idx  = blockIdx.x * 512 + threadIdx.x;   // 32768 = 512 codes * 64 d
  int code = idx >> 6, d = idx & 63;
  float s  = -2.0f * emb[code * 64 + d];
  unsigned u  = __float_as_uint(s);
  unsigned hi = (u + 0x7FFFu + ((u >> 16) & 1u)) >> 16;       // RNE bf16
  float lof   = s - __uint_as_float(hi << 16);
  unsigned v2 = __float_as_uint(lof);
  unsigned lo = (v2 + 0x7FFFu + ((v2 >> 16) & 1u)) >> 16;     // RNE bf16
  int tile = code >> 4, row = code & 15;
  int c = (d >> 5) & 1, g = (d >> 3) & 3, i = d & 7;
  int lane = row + (g << 4);
  size_t base = ((size_t)tile * 256 + (size_t)c * 128) * 8;
  ef[base + (size_t)(0 * 64 + lane) * 8 + i] = (unsigned short)hi;
  ef[base + (size_t)(1 * 64 + lane) * 8 + i] = (unsigned short)lo;
}

// RNE bf16 two-term split of 8 floats (two float4s) -> hi/lo bf16x8.
__device__ __forceinline__ void split8(float4 a, float4 b,
                                       bf16x8& h, bf16x8& lo) {
  float v[8] = {a.x, a.y, a.z, a.w, b.x, b.y, b.z, b.w};
#pragma unroll
  for (int i = 0; i < 8; ++i) {
    unsigned u  = __float_as_uint(v[i]);
    unsigned hi = (u + 0x7FFFu + ((u >> 16) & 1u)) >> 16;
    float lof   = v[i] - __uint_as_float(hi << 16);
    unsigned v2 = __float_as_uint(lof);
    unsigned l2 = (v2 + 0x7FFFu + ((v2 >> 16) & 1u)) >> 16;
    h[i]  = (short)hi;
    lo[i] = (short)l2;
  }
}

#define ARGMIN4(C, BASE, BEST, SECOND, BIDXV)               \
  {                                                         \
    _Pragma("unroll")                                       \
    for (int r = 0; r < 4; ++r) {                           \
      float v = (C)[r];                                     \
      bool lt = v < (BEST);                                 \
      float mn = fminf((SECOND), v);                        \
      (SECOND) = lt ? (BEST) : mn;                          \
      (BIDXV)  = lt ? ((BASE) + r) : (BIDXV);               \
      (BEST)   = lt ? v : (BEST);                           \
    }                                                       \
  }

// ---- kernel A: MFMA distances, 32 tokens/wave ------------------------------
__global__ __launch_bounds__(256) void vq_mfma(
    const float* __restrict__ z_e, const unsigned short* __restrict__ efrag,
    const float* __restrict__ esq_g, int* __restrict__ bidx,
    unsigned* __restrict__ list, unsigned* __restrict__ cnt) {
  __shared__ float esql[K];                        // 2048 B
  __shared__ __align__(16) short lds_eb[2][4096];  // 2 x 8KB (tile-pair dbuf)

  const int t  = threadIdx.x;
  const int l  = t & 63;
  const int w  = t >> 6;
  const int wu = __builtin_amdgcn_readfirstlane(w);  // SGPR wave id
  const int g  = l >> 4, g4 = g << 2;
  const int gtok0 = blockIdx.x * 128;

  esql[t] = esq_g[t];
  esql[t + 256] = esq_g[t + 256];

  // z frags for two token rows, direct from global (each row read once,
  // 4 lanes x 32B per 128B segment -> coalesced). RNE split = efrag's.
  bf16x8 zh0A, zl0A, zh1A, zl1A, zh0B, zl0B, zh1B, zl1B;
  {
    const int rowA = gtok0 + w * 32 + (l & 15);
    const float* zp = z_e + (size_t)rowA * D + g * 8;
    float4 q0 = *reinterpret_cast<const float4*>(zp);
    float4 q1 = *reinterpret_cast<const float4*>(zp + 4);
    float4 q2 = *reinterpret_cast<const float4*>(zp + 32);
    float4 q3 = *reinterpret_cast<const float4*>(zp + 36);
    split8(q0, q1, zh0A, zl0A);
    split8(q2, q3, zh1A, zl1A);
    zp += (size_t)16 * D;                          // rowB = rowA + 16
    q0 = *reinterpret_cast<const float4*>(zp);
    q1 = *reinterpret_cast<const float4*>(zp + 4);
    q2 = *reinterpret_cast<const float4*>(zp + 32);
    q3 = *reinterpret_cast<const float4*>(zp + 36);
    split8(q0, q1, zh0B, zl0B);
    split8(q2, q3, zh1B, zl1B);
  }

  const bf16x8* EF = reinterpret_cast<const bf16x8*>(efrag);
  // Prime tile-pair 0 into buffer 0 (global -> LDS direct, 16B/lane).
  GLDS16(EF + t,       &lds_eb[0][wu * 512]);
  GLDS16(EF + 256 + t, &lds_eb[0][2048 + wu * 512]);
  __syncthreads();

  float bestA = 3.402823466e38f, secondA = 3.402823466e38f;
  float bestB = 3.402823466e38f, secondB = 3.402823466e38f;
  int idxA = 0, idxB = 0;
  int buf = 0;

  for (int it = 0; it < 16; ++it) {
    if (it < 15) {                                 // stage next pair early
      const bf16x8* src = EF + (size_t)(it + 1) * 512;
      GLDS16(src + t,       &lds_eb[buf ^ 1][wu * 512]);
      GLDS16(src + 256 + t, &lds_eb[buf ^ 1][2048 + wu * 512]);
    }
    const bf16x8* eb = reinterpret_cast<const bf16x8*>(&lds_eb[buf][0]);

#pragma unroll
    for (int half = 0; half < 2; ++half) {
      const int tile = 2 * it + half;
      const bf16x8* tb = eb + half * 256;
      f32x4 CA = *reinterpret_cast<const f32x4*>(&esql[tile * 16 + g4]);
      f32x4 CB = CA;
      // k-chunk 0: per-chain order Eh*Zh, Eh*Zl, El*Zh  (== R12 bitwise)
      bf16x8 e0h = tb[l], e0l = tb[64 + l];
      CA = __builtin_amdgcn_mfma_f32_16x16x32_bf16(e0h, zh0A, CA, 0, 0, 0);
      CB = __builtin_amdgcn_mfma_f32_16x16x32_bf16(e0h, zh0B, CB, 0, 0, 0);
      CA = __builtin_amdgcn_mfma_f32_16x16x32_bf16(e0h, zl0A, CA, 0, 0, 0);
      CB = __builtin_amdgcn_mfma_f32_16x16x32_bf16(e0h, zl0B, CB, 0, 0, 0);
      CA = __builtin_amdgcn_mfma_f32_16x16x32_bf16(e0l, zh0A, CA, 0, 0, 0);
      CB = __builtin_amdgcn_mfma_f32_16x16x32_bf16(e0l, zh0B, CB, 0, 0, 0);
      // k-chunk 1
      bf16x8 e1h = tb[128 + l], e1l = tb[192 + l];
      CA = __builtin_amdgcn_mfma_f32_16x16x32_bf16(e1h, zh1A, CA, 0, 0, 0);
      CB = __builtin_amdgcn_mfma_f32_16x16x32_bf16(e1h, zh1B, CB, 0, 0, 0);
      CA = __builtin_amdgcn_mfma_f32_16x16x32_bf16(e1h, zl1A, CA, 0, 0, 0);
      CB = __builtin_amdgcn_mfma_f32_16x16x32_bf16(e1h, zl1B, CB, 0, 0, 0);
      CA = __builtin_amdgcn_mfma_f32_16x16x32_bf16(e1l, zh1A, CA, 0, 0, 0);
      CB = __builtin_amdgcn_mfma_f32_16x16x32_bf16(e1l, zh1B, CB, 0, 0, 0);

      const int base = tile * 16 + g4;             // ascending code order
      ARGMIN4(CA, base, bestA, secondA, idxA)
      ARGMIN4(CB, base, bestB, secondB, idxB)
    }
    __syncthreads();                               // drains vmcnt -> buf^1 ready
    buf ^= 1;
  }

  // Reduce each group across lanes {l, l^16, l^32, l^48}; ties -> smaller code.
#pragma unroll
  for (int mask = 16; mask <= 32; mask <<= 1) {
    float ob, os; int oi; bool take; float hi2;
    ob = __shfl_xor(bestA, mask); oi = __shfl_xor(idxA, mask);
    os = __shfl_xor(secondA, mask);
    hi2 = fmaxf(bestA, ob);
    secondA = fminf(secondA, fminf(os, hi2));
    take = (ob < bestA) || (ob == bestA && oi < idxA);
    bestA = take ? ob : bestA; idxA = take ? oi : idxA;

    ob = __shfl_xor(bestB, mask); oi = __shfl_xor(idxB, mask);
    os = __shfl_xor(secondB, mask);
    hi2 = fmaxf(bestB, ob);
    secondB = fminf(secondB, fminf(os, hi2));
    take = (ob < bestB) || (ob == bestB && oi < idxB);
    bestB = take ? ob : bestB; idxB = take ? oi : idxB;
  }

  if (l < 16) {
    const int nA = gtok0 + w * 32 + l;
    bool fA = (secondA - bestA) < THRESH;          // gap guard
    bidx[nA] = idxA | (fA ? 0x40000000 : 0);
    if (fA) { unsigned p = atomicAdd(cnt, 1u); list[p] = (unsigned)nA; }
    const int nB = nA + 16;
    bool fB = (secondB - bestB) < THRESH;
    bidx[nB] = idxB | (fB ? 0x40000000 : 0);
    if (fB) { unsigned p = atomicAdd(cnt, 1u); list[p] = (unsigned)nB; }
  }
}

// ---- kernel B: exact f32 rescan of flagged tokens (wave per token) ---------
__global__ __launch_bounds__(256) void vq_fix(
    const float* __restrict__ z_e, const float* __restrict__ emb,
    const float* __restrict__ esq_g, int* __restrict__ bidx,
    const unsigned* __restrict__ list, const unsigned* __restrict__ cnt) {
  const int l = threadIdx.x & 63;
  const int wid = blockIdx.x * 4 + (threadIdx.x >> 6);
  const unsigned n_flag = *cnt;
  for (unsigned j = wid; j < n_flag; j += 256 * 4) {
    const int n = (int)list[j];
    const float4* zr = reinterpret_cast<const float4*>(z_e + (size_t)n * D);
    float acc[8];
#pragma unroll
    for (int m = 0; m < 8; ++m) acc[m] = 0.f;
#pragma unroll 4
    for (int i = 0; i < 16; ++i) {
      float4 z4 = zr[i];
#pragma unroll
      for (int m = 0; m < 8; ++m) {
        const float4 e4 = *reinterpret_cast<const float4*>(
            emb + (size_t)(l + 64 * m) * D + 4 * i);
        acc[m] = fmaf(z4.x, e4.x, acc[m]);
        acc[m] = fmaf(z4.y, e4.y, acc[m]);
        acc[m] = fmaf(z4.z, e4.z, acc[m]);
        acc[m] = fmaf(z4.w, e4.w, acc[m]);
      }
    }
    float best = 3.402823466e38f; int bid = 0;
#pragma unroll
    for (int m = 0; m < 8; ++m) {
      float s = fmaf(-2.f, acc[m], esq_g[l + 64 * m]);
      if (s < best) { best = s; bid = l + 64 * m; }
    }
#pragma unroll
    for (int mask = 1; mask <= 32; mask <<= 1) {     // lexicographic min
      float ob = __shfl_xor(best, mask);
      int   oi = __shfl_xor(bid, mask);
      bool take = (ob < best) || (ob == best && oi < bid);
      best = take ? ob : best;
      bid  = take ? oi : bid;
    }
    if (l == 0) bidx[n] = bid;
  }
}

// ---- kernel C: gather + z_q_st + idx float + deterministic loss ------------
__global__ __launch_bounds__(256) void vq_out(
    const float* __restrict__ z_e, const float* __restrict__ emb,
    const int* __restrict__ bidx, float* __restrict__ out_zq,
    float* __restrict__ out_idx, float* __restrict__ block_loss) {
  __shared__ float wsm[4];
  const int t = threadIdx.x;
  const int tokE = t >> 2, q = t & 3;
  const int n = blockIdx.x * 64 + tokE;
  const int bi = bidx[n] & 511;
  const float4* er = reinterpret_cast<const float4*>(emb + (size_t)bi * D);
  const float4* zr = reinterpret_cast<const float4*>(z_e + (size_t)n * D);
  float4* orow = reinterpret_cast<float4*>(out_zq + (size_t)n * D);
  float lsum = 0.f;
#pragma unroll
  for (int j = 0; j < 4; ++j) {
    int i = 4 * q + j;
    float4 Q = er[i], Z = zr[i];
    float dx = Q.x - Z.x, dy = Q.y - Z.y, dz = Q.z - Z.z, dw = Q.w - Z.w;
    float4 st;
    st.x = Z.x + dx; st.y = Z.y + dy; st.z = Z.z + dz; st.w = Z.w + dw;
    orow[i] = st;
    lsum = fmaf(dx, dx, lsum); lsum = fmaf(dy, dy, lsum);
    lsum = fmaf(dz, dz, lsum); lsum = fmaf(dw, dw, lsum);
  }
  if (q == 0) out_idx[n] = (float)bi;
  float s = lsum;
#pragma unroll
  for (int off = 32; off > 0; off >>= 1) s += __shfl_xor(s, off, 64);
  if ((t & 63) == 0) wsm[t >> 6] = s;
  __syncthreads();
  if (t == 0) block_loss[blockIdx.x] = ((wsm[0] + wsm[1]) + wsm[2]) + wsm[3];
}

// ---- finalize loss (deterministic tree) ------------------------------------
__global__ __launch_bounds__(256) void loss_finalize(
    const float* __restrict__ bl, float* __restrict__ out_loss) {
  __shared__ float sm[256];
  float s = 0.f;
  for (int i = threadIdx.x; i < NBLK_OUT; i += 256) s += bl[i];
  sm[threadIdx.x] = s;
  __syncthreads();
#pragma unroll
  for (int off = 128; off > 0; off >>= 1) {
    if (threadIdx.x < off) sm[threadIdx.x] += sm[threadIdx.x + off];
    __syncthreads();
  }
  if (threadIdx.x == 0) out_loss[0] = sm[0] * (1.0f / 16777216.0f);  // /(N*D)
}

extern "C" void kernel_launch(void* const* d_in, const int* in_sizes, int n_in,
                              void* d_out, int out_size, void* d_ws, size_t ws_size,
                              hipStream_t stream) {
  const float* z_e = (const float*)d_in[0];
  const float* emb = (const float*)d_in[1];

  float* out      = (float*)d_out;
  float* out_zq   = out;                          // N*D
  float* out_idx  = out + (size_t)N_TOK * D;      // N
  float* out_loss = out_idx + N_TOK;              // 1

  char* wsb = (char*)d_ws;
  float*          esqp = (float*)(wsb + WS_ESQ);
  float*          bl   = (float*)(wsb + WS_BL);
  unsigned*       cntp = (unsigned*)(wsb + WS_CNT);
  unsigned short* ef   = (unsigned short*)(wsb + WS_EFRAG);
  int*            bidx = (int*)(wsb + WS_BIDX);
  unsigned*       list = (unsigned*)(wsb + WS_LIST);

  hipMemsetAsync(cntp, 0, 4, stream);
  esq_kernel<<<1, 512, 0, stream>>>(emb, esqp);
  efrag_kernel<<<64, 512, 0, stream>>>(emb, ef);
  vq_mfma<<<N_TOK / 128, 256, 0, stream>>>(z_e, ef, esqp, bidx, list, cntp);
  vq_fix<<<256, 256, 0, stream>>>(z_e, emb, esqp, bidx, list, cntp);
  vq_out<<<NBLK_OUT, 256, 0, stream>>>(z_e, emb, bidx, out_zq, out_idx, bl);
  loss_finalize<<<1, 256, 0, stream>>>(bl, out_loss);
}

// Round 14
// 159.827 us; speedup vs baseline: 1.2026x; 1.0029x over previous
//
#include <hip/hip_runtime.h>

// VQ codebook via MFMA: z_e (262144,64) f32, embeddings (512,64) f32.
// Outputs (flat f32): z_q_st [N*D], indices-as-float [N], loss [1].
//
// R14 = R13 hot loop (bitwise identical MFMA/split/argmin; passed absmax 0)
// + FUSED epilogue: winning indices -> LDS -> all 256 threads gather/write
// z_q_st + out_idx + block loss inside vq_mfma (vq_out kernel and bidx
// buffer deleted; z rows L2/L3-hot). vq_fix now also patches the flagged
// rows/index and writes per-token loss DELTAS into a zeroed dl[] (fixed
// slots -> deterministic). s_setprio(1) around MFMA clusters (T5).
// R13 lesson: secondary kernels were 74us of the 160; vq_mfma's own stall
// (phase collision) is the remaining structural item.

typedef short  bf16x8 __attribute__((ext_vector_type(8)));
typedef float  f32x4  __attribute__((ext_vector_type(4)));

static constexpr int N_TOK = 262144;
static constexpr int K     = 512;
static constexpr int D     = 64;
static constexpr float THRESH = 0.02f;
static constexpr int NBLK_A = N_TOK / 128;    // 2048 vq_mfma blocks

// ws layout (bytes)
static constexpr size_t WS_ESQ   = 0;         //  512 f32 (2048 B)
static constexpr size_t WS_BL    = 2048;      // 2048 f32 (8192 B)
static constexpr size_t WS_CNT   = 10240;     // 1 uint
static constexpr size_t WS_EFRAG = 10256;     // 65536 u16 (131072 B), 16B-al
static constexpr size_t WS_DBL   = 141328;    // 256 f32
static constexpr size_t WS_LIST  = 142352;    // 262144 uint (1 MB)
static constexpr size_t WS_DL    = 1190928;   // 262144 f32  (1 MB)

#define GLDS16(G, L) __builtin_amdgcn_global_load_lds(                    \
    (const __attribute__((address_space(1))) void*)(G),                   \
    (__attribute__((address_space(3))) void*)(L), 16, 0, 0)

// ---- prep 0: esq[k] = ||e_k||^2 (f32) --------------------------------------
__global__ void esq_kernel(const float* __restrict__ emb, float* __restrict__ esq) {
  int k = threadIdx.x;
  if (k < K) {
    const float4* row = reinterpret_cast<const float4*>(emb + (size_t)k * D);
    float s = 0.f;
#pragma unroll
    for (int i = 0; i < D / 4; ++i) {
      float4 v = row[i];
      s = fmaf(v.x, v.x, s); s = fmaf(v.y, v.y, s);
      s = fmaf(v.z, v.z, s); s = fmaf(v.w, v.w, s);
    }
    esq[k] = s;
  }
}

// ---- prep 1: E' = -2E -> bf16 hi/lo in A-fragment order --------------------
__global__ __launch_bounds__(512) void efrag_kernel(
    const float* __restrict__ emb, unsigned short* __restrict__ ef) {
  int idx  = blockIdx.x * 512 + threadIdx.x;   // 32768 = 512 codes * 64 d
  int code = idx >> 6, d = idx & 63;
  float s  = -2.0f * emb[code * 64 + d];
  unsigned u  = __float_as_uint(s);
  unsigned hi = (u + 0x7FFFu + ((u >> 16) & 1u)) >> 16;       // RNE bf16
  float lof   = s - __uint_as_float(hi << 16);
  unsigned v2 = __float_as_uint(lof);
  unsigned lo = (v2 + 0x7FFFu + ((v2 >> 16) & 1u)) >> 16;     // RNE bf16
  int tile = code >> 4, row = code & 15;
  int c = (d >> 5) & 1, g = (d >> 3) & 3, i = d & 7;
  int lane = row + (g << 4);
  size_t base = ((size_t)tile * 256 + (size_t)c * 128) * 8;
  ef[base + (size_t)(0 * 64 + lane) * 8 + i] = (unsigned short)hi;
  ef[base + (size_t)(1 * 64 + lane) * 8 + i] = (unsigned short)lo;
}

// RNE bf16 two-term split of 8 floats -> hi/lo bf16x8.
__device__ __forceinline__ void split8(float4 a, float4 b,
                                       bf16x8& h, bf16x8& lo) {
  float v[8] = {a.x, a.y, a.z, a.w, b.x, b.y, b.z, b.w};
#pragma unroll
  for (int i = 0; i < 8; ++i) {
    unsigned u  = __float_as_uint(v[i]);
    unsigned hi = (u + 0x7FFFu + ((u >> 16) & 1u)) >> 16;
    float lof   = v[i] - __uint_as_float(hi << 16);
    unsigned v2 = __float_as_uint(lof);
    unsigned l2 = (v2 + 0x7FFFu + ((v2 >> 16) & 1u)) >> 16;
    h[i]  = (short)hi;
    lo[i] = (short)l2;
  }
}

#define ARGMIN4(C, BASE, BEST, SECOND, BIDXV)               \
  {                                                         \
    _Pragma("unroll")                                       \
    for (int r = 0; r < 4; ++r) {                           \
      float v = (C)[r];                                     \
      bool lt = v < (BEST);                                 \
      float mn = fminf((SECOND), v);                        \
      (SECOND) = lt ? (BEST) : mn;                          \
      (BIDXV)  = lt ? ((BASE) + r) : (BIDXV);               \
      (BEST)   = lt ? v : (BEST);                           \
    }                                                       \
  }

// ---- kernel A: MFMA distances + fused gather/write/loss --------------------
__global__ __launch_bounds__(256) void vq_mfma(
    const float* __restrict__ z_e, const float* __restrict__ emb,
    const unsigned short* __restrict__ efrag, const float* __restrict__ esq_g,
    float* __restrict__ out_zq, float* __restrict__ out_idx,
    float* __restrict__ block_loss, unsigned* __restrict__ list,
    unsigned* __restrict__ cnt) {
  __shared__ float esql[K];                        // 2048 B
  __shared__ __align__(16) short lds_eb[2][4096];  // 2 x 8KB (tile-pair dbuf)
  __shared__ int   sIdx[128];
  __shared__ float wsm[4];

  const int t  = threadIdx.x;
  const int l  = t & 63;
  const int w  = t >> 6;
  const int wu = __builtin_amdgcn_readfirstlane(w);  // SGPR wave id
  const int g  = l >> 4, g4 = g << 2;
  const int gtok0 = blockIdx.x * 128;

  esql[t] = esq_g[t];
  esql[t + 256] = esq_g[t + 256];

  // z frags for two token rows, direct from global. RNE split = efrag's.
  bf16x8 zh0A, zl0A, zh1A, zl1A, zh0B, zl0B, zh1B, zl1B;
  {
    const int rowA = gtok0 + w * 32 + (l & 15);
    const float* zp = z_e + (size_t)rowA * D + g * 8;
    float4 q0 = *reinterpret_cast<const float4*>(zp);
    float4 q1 = *reinterpret_cast<const float4*>(zp + 4);
    float4 q2 = *reinterpret_cast<const float4*>(zp + 32);
    float4 q3 = *reinterpret_cast<const float4*>(zp + 36);
    split8(q0, q1, zh0A, zl0A);
    split8(q2, q3, zh1A, zl1A);
    zp += (size_t)16 * D;                          // rowB = rowA + 16
    q0 = *reinterpret_cast<const float4*>(zp);
    q1 = *reinterpret_cast<const float4*>(zp + 4);
    q2 = *reinterpret_cast<const float4*>(zp + 32);
    q3 = *reinterpret_cast<const float4*>(zp + 36);
    split8(q0, q1, zh0B, zl0B);
    split8(q2, q3, zh1B, zl1B);
  }

  const bf16x8* EF = reinterpret_cast<const bf16x8*>(efrag);
  GLDS16(EF + t,       &lds_eb[0][wu * 512]);
  GLDS16(EF + 256 + t, &lds_eb[0][2048 + wu * 512]);
  __syncthreads();

  float bestA = 3.402823466e38f, secondA = 3.402823466e38f;
  float bestB = 3.402823466e38f, secondB = 3.402823466e38f;
  int idxA = 0, idxB = 0;
  int buf = 0;

  for (int it = 0; it < 16; ++it) {
    if (it < 15) {                                 // stage next pair early
      const bf16x8* src = EF + (size_t)(it + 1) * 512;
      GLDS16(src + t,       &lds_eb[buf ^ 1][wu * 512]);
      GLDS16(src + 256 + t, &lds_eb[buf ^ 1][2048 + wu * 512]);
    }
    const bf16x8* eb = reinterpret_cast<const bf16x8*>(&lds_eb[buf][0]);

#pragma unroll
    for (int half = 0; half < 2; ++half) {
      const int tile = 2 * it + half;
      const bf16x8* tb = eb + half * 256;
      f32x4 CA = *reinterpret_cast<const f32x4*>(&esql[tile * 16 + g4]);
      f32x4 CB = CA;
      bf16x8 e0h = tb[l], e0l = tb[64 + l];
      bf16x8 e1h = tb[128 + l], e1l = tb[192 + l];
      __builtin_amdgcn_s_setprio(1);
      CA = __builtin_amdgcn_mfma_f32_16x16x32_bf16(e0h, zh0A, CA, 0, 0, 0);
      CB = __builtin_amdgcn_mfma_f32_16x16x32_bf16(e0h, zh0B, CB, 0, 0, 0);
      CA = __builtin_amdgcn_mfma_f32_16x16x32_bf16(e0h, zl0A, CA, 0, 0, 0);
      CB = __builtin_amdgcn_mfma_f32_16x16x32_bf16(e0h, zl0B, CB, 0, 0, 0);
      CA = __builtin_amdgcn_mfma_f32_16x16x32_bf16(e0l, zh0A, CA, 0, 0, 0);
      CB = __builtin_amdgcn_mfma_f32_16x16x32_bf16(e0l, zh0B, CB, 0, 0, 0);
      CA = __builtin_amdgcn_mfma_f32_16x16x32_bf16(e1h, zh1A, CA, 0, 0, 0);
      CB = __builtin_amdgcn_mfma_f32_16x16x32_bf16(e1h, zh1B, CB, 0, 0, 0);
      CA = __builtin_amdgcn_mfma_f32_16x16x32_bf16(e1h, zl1A, CA, 0, 0, 0);
      CB = __builtin_amdgcn_mfma_f32_16x16x32_bf16(e1h, zl1B, CB, 0, 0, 0);
      CA = __builtin_amdgcn_mfma_f32_16x16x32_bf16(e1l, zh1A, CA, 0, 0, 0);
      CB = __builtin_amdgcn_mfma_f32_16x16x32_bf16(e1l, zh1B, CB, 0, 0, 0);
      __builtin_amdgcn_s_setprio(0);

      const int base = tile * 16 + g4;             // ascending code order
      ARGMIN4(CA, base, bestA, secondA, idxA)
      ARGMIN4(CB, base, bestB, secondB, idxB)
    }
    __syncthreads();
    buf ^= 1;
  }

  // Reduce each group across lanes {l, l^16, l^32, l^48}; ties -> smaller code.
#pragma unroll
  for (int mask = 16; mask <= 32; mask <<= 1) {
    float ob, os; int oi; bool take; float hi2;
    ob = __shfl_xor(bestA, mask); oi = __shfl_xor(idxA, mask);
    os = __shfl_xor(secondA, mask);
    hi2 = fmaxf(bestA, ob);
    secondA = fminf(secondA, fminf(os, hi2));
    take = (ob < bestA) || (ob == bestA && oi < idxA);
    bestA = take ? ob : bestA; idxA = take ? oi : idxA;

    ob = __shfl_xor(bestB, mask); oi = __shfl_xor(idxB, mask);
    os = __shfl_xor(secondB, mask);
    hi2 = fmaxf(bestB, ob);
    secondB = fminf(secondB, fminf(os, hi2));
    take = (ob < bestB) || (ob == bestB && oi < idxB);
    bestB = take ? ob : bestB; idxB = take ? oi : idxB;
  }

  if (l < 16) {
    const int nA = gtok0 + w * 32 + l;
    sIdx[w * 32 + l] = idxA;
    if ((secondA - bestA) < THRESH) {              // gap guard
      unsigned p = atomicAdd(cnt, 1u); list[p] = (unsigned)nA;
    }
    const int nB = nA + 16;
    sIdx[w * 32 + 16 + l] = idxB;
    if ((secondB - bestB) < THRESH) {
      unsigned p = atomicAdd(cnt, 1u); list[p] = (unsigned)nB;
    }
  }
  __syncthreads();

  // Fused epilogue: 2 threads/token; gather + z_q_st + idx + loss.
  {
    const int tk = t >> 1, h = t & 1;
    const int n = gtok0 + tk;
    const int bi = sIdx[tk];
    const float4* er = reinterpret_cast<const float4*>(emb + (size_t)bi * D);
    const float4* zr = reinterpret_cast<const float4*>(z_e + (size_t)n * D);
    float4* orow = reinterpret_cast<float4*>(out_zq + (size_t)n * D);
    float lsum = 0.f;
#pragma unroll
    for (int j = 0; j < 8; ++j) {
      int i = h * 8 + j;
      float4 Q = er[i], Z = zr[i];
      float dx = Q.x - Z.x, dy = Q.y - Z.y, dz = Q.z - Z.z, dw = Q.w - Z.w;
      float4 st;
      st.x = Z.x + dx; st.y = Z.y + dy; st.z = Z.z + dz; st.w = Z.w + dw;
      orow[i] = st;
      lsum = fmaf(dx, dx, lsum); lsum = fmaf(dy, dy, lsum);
      lsum = fmaf(dz, dz, lsum); lsum = fmaf(dw, dw, lsum);
    }
    if (h == 0) out_idx[n] = (float)bi;
    float s = lsum;
#pragma unroll
    for (int off = 32; off > 0; off >>= 1) s += __shfl_xor(s, off, 64);
    if (l == 0) wsm[w] = s;
  }
  __syncthreads();
  if (t == 0) block_loss[blockIdx.x] = ((wsm[0] + wsm[1]) + wsm[2]) + wsm[3];
}

// ---- kernel B: exact rescan of flagged tokens + row/idx/loss patch ---------
__global__ __launch_bounds__(256) void vq_fix(
    const float* __restrict__ z_e, const float* __restrict__ emb,
    const float* __restrict__ esq_g, float* __restrict__ out_zq,
    float* __restrict__ out_idx, float* __restrict__ dl,
    const unsigned* __restrict__ list, const unsigned* __restrict__ cnt) {
  const int l = threadIdx.x & 63;
  const int wid = blockIdx.x * 4 + (threadIdx.x >> 6);
  const unsigned n_flag = *cnt;
  for (unsigned j = wid; j < n_flag; j += 256 * 4) {
    const int n = (int)list[j];
    const int old = (int)out_idx[n];
    const float4* zr = reinterpret_cast<const float4*>(z_e + (size_t)n * D);
    float acc[8];
#pragma unroll
    for (int m = 0; m < 8; ++m) acc[m] = 0.f;
#pragma unroll 4
    for (int i = 0; i < 16; ++i) {
      float4 z4 = zr[i];
#pragma unroll
      for (int m = 0; m < 8; ++m) {
        const float4 e4 = *reinterpret_cast<const float4*>(
            emb + (size_t)(l + 64 * m) * D + 4 * i);
        acc[m] = fmaf(z4.x, e4.x, acc[m]);
        acc[m] = fmaf(z4.y, e4.y, acc[m]);
        acc[m] = fmaf(z4.z, e4.z, acc[m]);
        acc[m] = fmaf(z4.w, e4.w, acc[m]);
      }
    }
    float best = 3.402823466e38f; int bid = 0;
#pragma unroll
    for (int m = 0; m < 8; ++m) {
      float s = fmaf(-2.f, acc[m], esq_g[l + 64 * m]);
      if (s < best) { best = s; bid = l + 64 * m; }
    }
#pragma unroll
    for (int mask = 1; mask <= 32; mask <<= 1) {     // lexicographic min
      float ob = __shfl_xor(best, mask);
      int   oi = __shfl_xor(bid, mask);
      bool take = (ob < best) || (ob == best && oi < bid);
      best = take ? ob : best;
      bid  = take ? oi : bid;
    }
    // Patch row + index + loss delta (fixed slots -> deterministic).
    float part = 0.f;
    if (l < 16) {
      float4 Z  = zr[l];
      float4 Qn = reinterpret_cast<const float4*>(emb + (size_t)bid * D)[l];
      float4 Qo = reinterpret_cast<const float4*>(emb + (size_t)old * D)[l];
      float nx = Qn.x - Z.x, ny = Qn.y - Z.y, nz = Qn.z - Z.z, nw = Qn.w - Z.w;
      float ox = Qo.x - Z.x, oy = Qo.y - Z.y, oz = Qo.z - Z.z, ow = Qo.w - Z.w;
      float4 st;
      st.x = Z.x + nx; st.y = Z.y + ny; st.z = Z.z + nz; st.w = Z.w + nw;
      reinterpret_cast<float4*>(out_zq + (size_t)n * D)[l] = st;
      float dn = 0.f, po = 0.f;
      dn = fmaf(nx, nx, dn); dn = fmaf(ny, ny, dn);
      dn = fmaf(nz, nz, dn); dn = fmaf(nw, nw, dn);
      po = fmaf(ox, ox, po); po = fmaf(oy, oy, po);
      po = fmaf(oz, oz, po); po = fmaf(ow, ow, po);
      part = dn - po;
    }
#pragma unroll
    for (int off = 32; off > 0; off >>= 1) part += __shfl_xor(part, off, 64);
    if (l == 0) { out_idx[n] = (float)bid; dl[n] = part; }
  }
}

// ---- dl pre-reduce: 256 blocks x 1024 entries ------------------------------
__global__ __launch_bounds__(256) void dl_reduce(
    const float* __restrict__ dl, float* __restrict__ dbl) {
  __shared__ float sm[256];
  const int t = threadIdx.x;
  const size_t b = (size_t)blockIdx.x * 1024;
  float s = dl[b + t] + dl[b + 256 + t] + dl[b + 512 + t] + dl[b + 768 + t];
  sm[t] = s;
  __syncthreads();
#pragma unroll
  for (int off = 128; off > 0; off >>= 1) {
    if (t < off) sm[t] += sm[t + off];
    __syncthreads();
  }
  if (t == 0) dbl[blockIdx.x] = sm[0];
}

// ---- finalize loss (deterministic tree) ------------------------------------
__global__ __launch_bounds__(256) void loss_finalize(
    const float* __restrict__ bl, const float* __restrict__ dbl,
    float* __restrict__ out_loss) {
  __shared__ float sm[256];
  const int t = threadIdx.x;
  float s = 0.f;
  for (int i = t; i < NBLK_A; i += 256) s += bl[i];
  s += dbl[t];
  sm[t] = s;
  __syncthreads();
#pragma unroll
  for (int off = 128; off > 0; off >>= 1) {
    if (t < off) sm[t] += sm[t + off];
    __syncthreads();
  }
  if (t == 0) out_loss[0] = sm[0] * (1.0f / 16777216.0f);  // /(N*D)
}

extern "C" void kernel_launch(void* const* d_in, const int* in_sizes, int n_in,
                              void* d_out, int out_size, void* d_ws, size_t ws_size,
                              hipStream_t stream) {
  const float* z_e = (const float*)d_in[0];
  const float* emb = (const float*)d_in[1];

  float* out      = (float*)d_out;
  float* out_zq   = out;                          // N*D
  float* out_idx  = out + (size_t)N_TOK * D;      // N
  float* out_loss = out_idx + N_TOK;              // 1

  char* wsb = (char*)d_ws;
  float*          esqp = (float*)(wsb + WS_ESQ);
  float*          bl   = (float*)(wsb + WS_BL);
  unsigned*       cntp = (unsigned*)(wsb + WS_CNT);
  unsigned short* ef   = (unsigned short*)(wsb + WS_EFRAG);
  float*          dbl  = (float*)(wsb + WS_DBL);
  unsigned*       list = (unsigned*)(wsb + WS_LIST);
  float*          dl   = (float*)(wsb + WS_DL);

  hipMemsetAsync(cntp, 0, 4, stream);
  hipMemsetAsync(dl, 0, (size_t)N_TOK * 4, stream);
  esq_kernel<<<1, 512, 0, stream>>>(emb, esqp);
  efrag_kernel<<<64, 512, 0, stream>>>(emb, ef);
  vq_mfma<<<NBLK_A, 256, 0, stream>>>(z_e, emb, ef, esqp, out_zq, out_idx,
                                      bl, list, cntp);
  vq_fix<<<256, 256, 0, stream>>>(z_e, emb, esqp, out_zq, out_idx, dl,
                                  list, cntp);
  dl_reduce<<<256, 256, 0, stream>>>(dl, dbl);
  loss_finalize<<<1, 256, 0, stream>>>(bl, dbl, out_loss);
}